// Round 12
// baseline (347.926 us; speedup 1.0000x reference)
//
#include <hip/hip_runtime.h>
#include <hip/hip_bf16.h>
#include <cstdint>

#define AS1 __attribute__((address_space(1)))
#define AS3 __attribute__((address_space(3)))

typedef __bf16 bf16x8 __attribute__((ext_vector_type(8)));
typedef float  f32x16 __attribute__((ext_vector_type(16)));

__device__ __forceinline__ void gld_lds16(const void* g, void* l) {
    __builtin_amdgcn_global_load_lds((const AS1 void*)g, (AS3 void*)l, 16, 0, 0);
}

// ---------------- Kernel 0: rotated 3x3 kernels + A-matrix build ----------------
// Block 0: w1 (exact fp32 replica of the bilinear rotation), threads 0..127.
// Blocks 1..1152: build the bf16 GEMM A matrix in MFMA-FRAGMENT-LINEAR order.
__global__ __launch_bounds__(256) void k_rot(const float* __restrict__ base,
                                             const float* __restrict__ w2,
                                             float* __restrict__ w1,
                                             __hip_bfloat16* __restrict__ A) {
    int tid = threadIdx.x;
    if (blockIdx.x == 0) {
        if (tid < 128) {
            int m = tid;                // 0..127 = g*16+o
            int g = m >> 4, o = m & 15;
            float th = 6.28318530717958647692f * (float)g / 8.0f;
            float c = cosf(th), s = sinf(th);
            for (int i = 0; i < 3; ++i) {
                float ys = (2.0f * i + 1.0f) / 3.0f - 1.0f;
                for (int j = 0; j < 3; ++j) {
                    float xs = (2.0f * j + 1.0f) / 3.0f - 1.0f;
                    float gx = c * xs - s * ys;
                    float gy = s * xs + c * ys;
                    float px = ((gx + 1.0f) * 3.0f - 1.0f) * 0.5f;
                    float py = ((gy + 1.0f) * 3.0f - 1.0f) * 0.5f;
                    float x0 = floorf(px), y0 = floorf(py);
                    float wx = px - x0, wy = py - y0;
                    int x0i = (int)x0, y0i = (int)y0;
                    auto gat = [&](int yi, int xi) -> float {
                        bool v = (yi >= 0) && (yi < 3) && (xi >= 0) && (xi < 3);
                        int yc = min(max(yi, 0), 2), xc = min(max(xi, 0), 2);
                        return v ? base[o * 9 + yc * 3 + xc] : 0.0f;
                    };
                    w1[m * 9 + i * 3 + j] =
                          gat(y0i, x0i)         * (1.0f - wx) * (1.0f - wy)
                        + gat(y0i, x0i + 1)     * wx          * (1.0f - wy)
                        + gat(y0i + 1, x0i)     * (1.0f - wx) * wy
                        + gat(y0i + 1, x0i + 1) * wx          * wy;
                }
            }
        }
    } else {
        int i = (blockIdx.x - 1) * 256 + tid;
        int r = i / 1152, k = i - r * 1152;
        int g = r >> 5, o2 = r & 31;
        int kk = k >> 7, cch = k & 127;
        int ky = kk / 3, kx = kk - ky * 3;
        int c2 = cch >> 3, hh = cch & 7;
        int gi = (g - hh) & 7;
        float val = w2[((o2 * 16 + c2) * 8 + gi) * 9 + ky * 3 + kx];
        // fragment-linear placement:
        //   A_byte = (t*2+mh)*16384 + (i2*4+ks)*1024 + (hi*32+row)*16 + e*2
        int half = cch >> 6, kt = cch & 63;
        int t = kk * 2 + half, ks2 = kt >> 4, hi2 = (kt >> 3) & 1, e = kt & 7;
        int mh = r >> 7, i2 = (r >> 5) & 3, row = r & 31;
        int aidx = ((((t * 2 + mh) * 16) + i2 * 4 + ks2) << 9) + ((hi2 << 5) + row) * 8 + e;
        A[aidx] = __float2bfloat16(val);
    }
}

// ---------------- Kernel 1: conv1 + relu -> channel-last padded bf16 h ----------------
// hl layout: [b][yy 0..29][xx 0..29][c 0..127], borders = 0.
// R11 post-mortem: conv1 is write-dominated (118 MB hl stores vs 1.6 MB reads) and
// the old per-thread scatter emitted 256B segments at 1KB stride. New output path:
// compute identically (same bf16 rounding -> bit-identical), store to a 16KB LDS
// tile [2][32][128], then block-linear copy the 60 valid pixels (15KB contiguous
// per block; each wave stores 1KB of consecutive 16B chunks).
__global__ __launch_bounds__(256) void k_conv1(const float* __restrict__ x,
                                               const float* __restrict__ w1g,
                                               __hip_bfloat16* __restrict__ hl) {
    int tid = threadIdx.x;

    __shared__ float w1s[1152];
    __shared__ __align__(16) __hip_bfloat16 hls[2][32][128];   // 16 KB
    for (int i = tid; i < 1152; i += 256) w1s[i] = w1g[i];
    __syncthreads();

    const int c0 = (tid & 15) * 8;
    float wreg[8][9];
#pragma unroll
    for (int cc = 0; cc < 8; ++cc)
#pragma unroll
        for (int k = 0; k < 9; ++k) wreg[cc][k] = w1s[(c0 + cc) * 9 + k];

    const int slot = tid >> 4;                    // 0..15
    const int band = blockIdx.x % 15;
    const int b    = blockIdx.x / 15;
    const int yyL  = slot >> 3;                   // 0..1 local row
    const int yy   = band * 2 + yyL;              // padded row 0..29
    const int xx0  = (slot & 7) * 4;              // 0,4,...,28

    const float* xb = x + b * 784;
    float xv[3][6];
#pragma unroll
    for (int t = 0; t < 3; ++t) {
        int sy = yy - 2 + t;
        bool syok = (sy >= 0) && (sy < 28);
#pragma unroll
        for (int u = 0; u < 6; ++u) {
            int sx = xx0 - 2 + u;
            bool ok = syok && (sx >= 0) && (sx < 28);
            xv[t][u] = ok ? xb[sy * 28 + sx] : 0.0f;
        }
    }

    float acc[4][8];
#pragma unroll
    for (int j = 0; j < 4; ++j)
#pragma unroll
        for (int cc = 0; cc < 8; ++cc) acc[j][cc] = 0.0f;

#pragma unroll
    for (int t = 0; t < 3; ++t)
#pragma unroll
        for (int u = 0; u < 3; ++u) {
#pragma unroll
            for (int j = 0; j < 4; ++j) {
                float xvv = xv[t][j + u];
#pragma unroll
                for (int cc = 0; cc < 8; ++cc)
                    acc[j][cc] += xvv * wreg[cc][t * 3 + u];
            }
        }

    // store to LDS tile (xx 30,31 cells written but never copied out)
#pragma unroll
    for (int j = 0; j < 4; ++j) {
        int xx = xx0 + j;
        bool interior = (yy >= 1) && (yy <= 28) && (xx >= 1) && (xx <= 28);
        union { __hip_bfloat16 h[8]; float4 f4; } u;
#pragma unroll
        for (int cc = 0; cc < 8; ++cc)
            u.h[cc] = __float2bfloat16(interior ? fmaxf(acc[j][cc], 0.0f) : 0.0f);
        *(float4*)(&hls[yyL][xx][c0]) = u.f4;
    }
    __syncthreads();

    // block-linear copy: 60 pixels x 16 float4 = 960 stores, fully contiguous
    float4* dst = (float4*)(hl + (size_t)(b * 900 + band * 60) * 128);
    for (int idx = tid; idx < 960; idx += 256) {
        int py  = idx >> 4, oct = idx & 15;
        int yl  = py / 30, xl = py - yl * 30;
        dst[idx] = *(const float4*)(&hls[yl][xl][oct * 8]);
    }
}

// ---------------- Kernel 2: conv2 implicit GEMM — R4/R10 (verified best: 228 µs) ----
// frag-linear A (32KB linear staging, lane-linear conflict-free reads) + XOR-swizzled
// B (pre-swizzled gld_lds source); 8 waves x 128x64; one __syncthreads per K-tile;
// SGB program pinning {staging, ks0-frags, 1:1 MFMA:ds_read interleave}.
__global__ __launch_bounds__(512, 2) void k_conv2(const __hip_bfloat16* __restrict__ A,
                                                  const __hip_bfloat16* __restrict__ hl,
                                                  __hip_bfloat16* __restrict__ p) {
    __shared__ __align__(16) char smem[131072];   // 2 x (A 32KB | B 32KB)

    const int tid  = threadIdx.x;
    const int lane = tid & 63;
    const int w    = tid >> 6;          // 0..7
    const int hi   = lane >> 5;
    const int wqr  = w >> 2;            // 0..1  M-group (128 rows each)
    const int wqc  = w & 3;             // 0..3  N-group (64 cols each)

    const int bid = blockIdx.x;         // grid 1568 = 8 * 196
    const int nt  = (bid & 7) * 196 + (bid >> 3);   // bijective XCD swizzle
    const int n0  = nt << 8;            // 256 N per tile

    // ---- B staging addresses: wave w stages ch = 2w+q of each 16KB half ----
    uint32_t bSrc[2][2], ldsCh[2];
#pragma unroll
    for (int q = 0; q < 2; ++q) {
        int ch = 2 * w + q;
        int rl = ch * 8 + (lane >> 3);                 // row within 128-row half
        int ca = (lane & 7) ^ (rl & 7) ^ (ch & 3);     // pre-swizzled 16B column
        ldsCh[q] = (uint32_t)(ch * 1024);
#pragma unroll
        for (int hn = 0; hn < 2; ++hn) {
            int n = n0 + hn * 128 + rl;
            int b = n / 784; int rr = n - b * 784;
            int y = rr / 28; int xx = rr - y * 28;
            bSrc[q][hn] = (uint32_t)(((b * 30 + y) * 30 + xx) * 256 + ca * 16);
        }
    }

    // ---- B fragment read addresses (2 frags per wave), relative to B base ----
    uint32_t bRd[2]; int bSw[2];
#pragma unroll
    for (int j = 0; j < 2; ++j) {
        int r = wqc * 64 + j * 32 + (lane & 31);       // 0..255
        bRd[j] = (uint32_t)((r >> 7) * 16384 + (r & 127) * 128);
        bSw[j] = (r & 7) ^ ((r >> 3) & 3);
    }

    // ---- A read base: wave's m-half block, lane-linear ----
    const uint32_t aRd = (uint32_t)(wqr * 16384 + lane * 16);

    f32x16 acc[4][2];
#pragma unroll
    for (int i = 0; i < 4; ++i)
#pragma unroll
        for (int j = 0; j < 2; ++j) acc[i][j] = (f32x16)(0.0f);

    const char* Ab = (const char*)A;
    const char* Hb = (const char*)hl;

    auto stage = [&](int tt, char* dst) {
        // A: contiguous 32KB at tt*32768, fully linear
#pragma unroll
        for (int q = 0; q < 4; ++q)
            gld_lds16(Ab + (size_t)tt * 32768 + q * 8192 + tid * 16,
                      dst + q * 8192 + tid * 16);
        // B: pre-swizzled source, linear dest
        int kk = tt >> 1, half = tt & 1;
        int ky = kk / 3, kx = kk - ky * 3;
        uint32_t boff = (uint32_t)((ky * 30 + kx) * 256 + half * 128);
        gld_lds16(Hb + bSrc[0][0] + boff, dst + 32768 + ldsCh[0]);
        gld_lds16(Hb + bSrc[1][0] + boff, dst + 32768 + ldsCh[1]);
        gld_lds16(Hb + bSrc[0][1] + boff, dst + 49152 + ldsCh[0]);
        gld_lds16(Hb + bSrc[1][1] + boff, dst + 49152 + ldsCh[1]);
    };

    // ---- prologue: stage tile 0 into buf0 ----
    stage(0, smem);

#pragma unroll 1
    for (int t = 0; t < 17; ++t) {
        __syncthreads();             // drains staging of tile t (issued last iter)
        char* cur = smem + ((t & 1) << 16);
        const char* LA = cur + aRd;
        const char* LB = cur + 32768;
        stage(t + 1, smem + (((t + 1) & 1) << 16));   // unconditional: body branch-free

        bf16x8 aF[2][4], bF[2][2];
        // ks0 fragments
#pragma unroll
        for (int i = 0; i < 4; ++i)
            aF[0][i] = *(const bf16x8*)(LA + ((i * 4 + 0) << 10));
#pragma unroll
        for (int j = 0; j < 2; ++j)
            bF[0][j] = *(const bf16x8*)(LB + bRd[j] + ((uint32_t)((0 + hi) ^ bSw[j]) << 4));

#pragma unroll
        for (int ks = 0; ks < 4; ++ks) {
            const int c = ks & 1, nx = c ^ 1;
            if (ks < 3) {
#pragma unroll
                for (int i = 0; i < 4; ++i)
                    aF[nx][i] = *(const bf16x8*)(LA + ((i * 4 + ks + 1) << 10));
#pragma unroll
                for (int j = 0; j < 2; ++j)
                    bF[nx][j] = *(const bf16x8*)(LB + bRd[j] + ((uint32_t)(((ks + 1) * 2 + hi) ^ bSw[j]) << 4));
            }
#pragma unroll
            for (int i = 0; i < 4; ++i)
#pragma unroll
                for (int j = 0; j < 2; ++j)
                    acc[i][j] = __builtin_amdgcn_mfma_f32_32x32x16_bf16(aF[c][i], bF[c][j], acc[i][j], 0, 0, 0);
        }

        // ---- scheduling program for this region ----
        // masks: MFMA=0x8, VMEM|VMEM_READ=0x30, DS_READ=0x100
        __builtin_amdgcn_sched_group_barrier(0x030, 8, 0);   // staging first
        __builtin_amdgcn_sched_group_barrier(0x100, 6, 0);   // ks0 frags
#pragma unroll
        for (int ks = 0; ks < 3; ++ks) {
#pragma unroll
            for (int r = 0; r < 6; ++r) {
                __builtin_amdgcn_sched_group_barrier(0x008, 1, 0);
                __builtin_amdgcn_sched_group_barrier(0x100, 1, 0);
            }
            __builtin_amdgcn_sched_group_barrier(0x008, 2, 0);
        }
        __builtin_amdgcn_sched_group_barrier(0x008, 8, 0);   // ks3 MFMAs
    }

    // ---- drain: tile 17 from buf1, no staging ----
    {
        __syncthreads();
        char* cur = smem + 65536;
        const char* LA = cur + aRd;
        const char* LB = cur + 32768;

        bf16x8 aF[2][4], bF[2][2];
#pragma unroll
        for (int i = 0; i < 4; ++i)
            aF[0][i] = *(const bf16x8*)(LA + ((i * 4 + 0) << 10));
#pragma unroll
        for (int j = 0; j < 2; ++j)
            bF[0][j] = *(const bf16x8*)(LB + bRd[j] + ((uint32_t)((0 + hi) ^ bSw[j]) << 4));

#pragma unroll
        for (int ks = 0; ks < 4; ++ks) {
            const int c = ks & 1, nx = c ^ 1;
            if (ks < 3) {
#pragma unroll
                for (int i = 0; i < 4; ++i)
                    aF[nx][i] = *(const bf16x8*)(LA + ((i * 4 + ks + 1) << 10));
#pragma unroll
                for (int j = 0; j < 2; ++j)
                    bF[nx][j] = *(const bf16x8*)(LB + bRd[j] + ((uint32_t)(((ks + 1) * 2 + hi) ^ bSw[j]) << 4));
            }
#pragma unroll
            for (int i = 0; i < 4; ++i)
#pragma unroll
                for (int j = 0; j < 2; ++j)
                    acc[i][j] = __builtin_amdgcn_mfma_f32_32x32x16_bf16(aF[c][i], bF[c][j], acc[i][j], 0, 0, 0);
        }
    }

    // ---- epilogue: relu + mean over 8 consecutive M-rows; bf16 store ----
#pragma unroll
    for (int i = 0; i < 4; ++i) {
#pragma unroll
        for (int j = 0; j < 2; ++j) {
            f32x16 v = acc[i][j];
#pragma unroll
            for (int u = 0; u < 4; ++u) {
                float sv = fmaxf(v[4*u], 0.0f) + fmaxf(v[4*u+1], 0.0f)
                         + fmaxf(v[4*u+2], 0.0f) + fmaxf(v[4*u+3], 0.0f);
                sv += __shfl_xor(sv, 32, 64);
                if (hi == 0) {
                    int a = wqr * 16 + i * 4 + u;
                    int n = n0 + wqc * 64 + j * 32 + (lane & 31);
                    int b = n / 784; int rr = n - b * 784;
                    p[(b * 32 + a) * 784 + rr] = __float2bfloat16(sv * 0.125f);
                }
            }
        }
    }
}

// ---------------- Kernel 3: FC — 8 images/block to amortize fw reads ----------------
__global__ __launch_bounds__(256) void k_fc(const __hip_bfloat16* __restrict__ p,
                                            const float* __restrict__ fw,
                                            const float* __restrict__ fb,
                                            float* __restrict__ out) {
    int bg = blockIdx.x >> 2, ks = blockIdx.x & 3;   // bg: 0..63, 8 images each
    int tid = threadIdx.x;
    const float4* w4 = (const float4*)fw;
    float acc[8][10];
#pragma unroll
    for (int bb = 0; bb < 8; ++bb)
#pragma unroll
        for (int c = 0; c < 10; ++c) acc[bb][c] = 0.0f;

    for (int t = ks * 784 + tid; t < (ks + 1) * 784; t += 256) {
        float4 u0[10], u1[10];
#pragma unroll
        for (int c = 0; c < 10; ++c) {
            u0[c] = w4[c * 6272 + 2 * t];
            u1[c] = w4[c * 6272 + 2 * t + 1];
        }
#pragma unroll
        for (int bb = 0; bb < 8; ++bb) {
            union { bf16x8 v; __hip_bfloat16 h[8]; } u;
            u.v = *(const bf16x8*)(p + (size_t)(bg * 8 + bb) * 25088 + (size_t)t * 8);
            float vf[8];
#pragma unroll
            for (int e = 0; e < 8; ++e) vf[e] = __bfloat162float(u.h[e]);
#pragma unroll
            for (int c = 0; c < 10; ++c)
                acc[bb][c] += vf[0] * u0[c].x + vf[1] * u0[c].y + vf[2] * u0[c].z + vf[3] * u0[c].w
                            + vf[4] * u1[c].x + vf[5] * u1[c].y + vf[6] * u1[c].z + vf[7] * u1[c].w;
        }
    }

    __shared__ float red[8][10][4];
    int lane = tid & 63, wv = tid >> 6;
#pragma unroll
    for (int bb = 0; bb < 8; ++bb)
#pragma unroll
        for (int c = 0; c < 10; ++c) {
            float s = acc[bb][c];
#pragma unroll
            for (int o = 32; o > 0; o >>= 1) s += __shfl_down(s, o, 64);
            if (lane == 0) red[bb][c][wv] = s;
        }
    __syncthreads();
    if (tid < 80) {
        int bb = tid / 10, c = tid - bb * 10;
        float s = red[bb][c][0] + red[bb][c][1] + red[bb][c][2] + red[bb][c][3];
        if (ks == 0) s += fb[c];
        atomicAdd(&out[(bg * 8 + bb) * 10 + c], s);
    }
}

// ---------------- launch ----------------
extern "C" void kernel_launch(void* const* d_in, const int* in_sizes, int n_in,
                              void* d_out, int out_size, void* d_ws, size_t ws_size,
                              hipStream_t stream) {
    const float* x  = (const float*)d_in[0];
    const float* bw = (const float*)d_in[1];
    const float* w2 = (const float*)d_in[2];
    const float* fw = (const float*)d_in[3];
    const float* fb = (const float*)d_in[4];
    float* out = (float*)d_out;
    char* ws = (char*)d_ws;

    float*          w1   = (float*)(ws);
    __hip_bfloat16* Amat = (__hip_bfloat16*)(ws + 4608);
    __hip_bfloat16* hl   = (__hip_bfloat16*)(ws + 594432);
    __hip_bfloat16* p    = (__hip_bfloat16*)(ws + 118563328);

    hipMemsetAsync(d_out, 0, (size_t)out_size * sizeof(float), stream);
    k_rot  <<<1153, 256, 0, stream>>>(bw, w2, w1, Amat);
    k_conv1<<<7680, 256, 0, stream>>>(x, w1, hl);
    k_conv2<<<1568, 512, 0, stream>>>(Amat, hl, p);
    k_fc   <<<256,  256, 0, stream>>>(p, fw, fb, out);
}

// Round 13
// 334.489 us; speedup vs baseline: 1.0402x; 1.0402x over previous
//
#include <hip/hip_runtime.h>
#include <hip/hip_bf16.h>
#include <cstdint>

#define AS1 __attribute__((address_space(1)))
#define AS3 __attribute__((address_space(3)))

typedef __bf16 bf16x8 __attribute__((ext_vector_type(8)));
typedef float  f32x16 __attribute__((ext_vector_type(16)));

__device__ __forceinline__ void gld_lds16(const void* g, void* l) {
    __builtin_amdgcn_global_load_lds((const AS1 void*)g, (AS3 void*)l, 16, 0, 0);
}

// ---------------- Kernel 0: rotated 3x3 kernels + A-matrix build ----------------
// Block 0: w1 (exact fp32 replica of the bilinear rotation), threads 0..127.
// Blocks 1..1152: build the bf16 GEMM A matrix in MFMA-FRAGMENT-LINEAR order.
__global__ __launch_bounds__(256) void k_rot(const float* __restrict__ base,
                                             const float* __restrict__ w2,
                                             float* __restrict__ w1,
                                             __hip_bfloat16* __restrict__ A) {
    int tid = threadIdx.x;
    if (blockIdx.x == 0) {
        if (tid < 128) {
            int m = tid;                // 0..127 = g*16+o
            int g = m >> 4, o = m & 15;
            float th = 6.28318530717958647692f * (float)g / 8.0f;
            float c = cosf(th), s = sinf(th);
            for (int i = 0; i < 3; ++i) {
                float ys = (2.0f * i + 1.0f) / 3.0f - 1.0f;
                for (int j = 0; j < 3; ++j) {
                    float xs = (2.0f * j + 1.0f) / 3.0f - 1.0f;
                    float gx = c * xs - s * ys;
                    float gy = s * xs + c * ys;
                    float px = ((gx + 1.0f) * 3.0f - 1.0f) * 0.5f;
                    float py = ((gy + 1.0f) * 3.0f - 1.0f) * 0.5f;
                    float x0 = floorf(px), y0 = floorf(py);
                    float wx = px - x0, wy = py - y0;
                    int x0i = (int)x0, y0i = (int)y0;
                    auto gat = [&](int yi, int xi) -> float {
                        bool v = (yi >= 0) && (yi < 3) && (xi >= 0) && (xi < 3);
                        int yc = min(max(yi, 0), 2), xc = min(max(xi, 0), 2);
                        return v ? base[o * 9 + yc * 3 + xc] : 0.0f;
                    };
                    w1[m * 9 + i * 3 + j] =
                          gat(y0i, x0i)         * (1.0f - wx) * (1.0f - wy)
                        + gat(y0i, x0i + 1)     * wx          * (1.0f - wy)
                        + gat(y0i + 1, x0i)     * (1.0f - wx) * wy
                        + gat(y0i + 1, x0i + 1) * wx          * wy;
                }
            }
        }
    } else {
        int i = (blockIdx.x - 1) * 256 + tid;
        int r = i / 1152, k = i - r * 1152;
        int g = r >> 5, o2 = r & 31;
        int kk = k >> 7, cch = k & 127;
        int ky = kk / 3, kx = kk - ky * 3;
        int c2 = cch >> 3, hh = cch & 7;
        int gi = (g - hh) & 7;
        float val = w2[((o2 * 16 + c2) * 8 + gi) * 9 + ky * 3 + kx];
        // fragment-linear placement:
        //   A_byte = (t*2+mh)*16384 + (i2*4+ks)*1024 + (hi*32+row)*16 + e*2
        int half = cch >> 6, kt = cch & 63;
        int t = kk * 2 + half, ks2 = kt >> 4, hi2 = (kt >> 3) & 1, e = kt & 7;
        int mh = r >> 7, i2 = (r >> 5) & 3, row = r & 31;
        int aidx = ((((t * 2 + mh) * 16) + i2 * 4 + ks2) << 9) + ((hi2 << 5) + row) * 8 + e;
        A[aidx] = __float2bfloat16(val);
    }
}

// ---------------- Kernel 1: conv1 + relu -> channel-last padded bf16 h ----------------
// hl layout: [b][yy 0..29][xx 0..29][c 0..127], borders = 0.
// R12 post-mortem: LDS-staged stores regressed (+22 µs) — direct 256B-segment
// stores were already fine. Real overhead: 7680 blocks each re-loading w1 (1152
// floats) + barrier before 60 pixels of work. Fix: ONE BLOCK PER IMAGE (grid 512),
// w1 loaded once, 15-band loop inside; band body identical to R11's verified
// direct-store code (bit-identical results). x (3KB/image) is L1-hot after band 0.
__global__ __launch_bounds__(256) void k_conv1(const float* __restrict__ x,
                                               const float* __restrict__ w1g,
                                               __hip_bfloat16* __restrict__ hl) {
    int tid = threadIdx.x;

    __shared__ float w1s[1152];
    for (int i = tid; i < 1152; i += 256) w1s[i] = w1g[i];
    __syncthreads();

    const int c0 = (tid & 15) * 8;
    float wreg[8][9];
#pragma unroll
    for (int cc = 0; cc < 8; ++cc)
#pragma unroll
        for (int k = 0; k < 9; ++k) wreg[cc][k] = w1s[(c0 + cc) * 9 + k];

    const int slot = tid >> 4;                    // 0..15
    const int b    = blockIdx.x;                  // one image per block
    const int yyL  = slot >> 3;                   // 0..1 local row
    const int xx0  = (slot & 7) * 4;              // 0,4,...,28
    const float* xb = x + b * 784;

#pragma unroll 1
    for (int band = 0; band < 15; ++band) {
        const int yy = band * 2 + yyL;            // padded row 0..29

        float xv[3][6];
#pragma unroll
        for (int t = 0; t < 3; ++t) {
            int sy = yy - 2 + t;
            bool syok = (sy >= 0) && (sy < 28);
#pragma unroll
            for (int u = 0; u < 6; ++u) {
                int sx = xx0 - 2 + u;
                bool ok = syok && (sx >= 0) && (sx < 28);
                xv[t][u] = ok ? xb[sy * 28 + sx] : 0.0f;
            }
        }

        float acc[4][8];
#pragma unroll
        for (int j = 0; j < 4; ++j)
#pragma unroll
            for (int cc = 0; cc < 8; ++cc) acc[j][cc] = 0.0f;

#pragma unroll
        for (int t = 0; t < 3; ++t)
#pragma unroll
            for (int u = 0; u < 3; ++u) {
#pragma unroll
                for (int j = 0; j < 4; ++j) {
                    float xvv = xv[t][j + u];
#pragma unroll
                    for (int cc = 0; cc < 8; ++cc)
                        acc[j][cc] += xvv * wreg[cc][t * 3 + u];
                }
            }

#pragma unroll
        for (int j = 0; j < 4; ++j) {
            int xx = xx0 + j;
            if (xx < 30) {
                bool interior = (yy >= 1) && (yy <= 28) && (xx >= 1) && (xx <= 28);
                union { __hip_bfloat16 h[8]; float4 f4; } u;
#pragma unroll
                for (int cc = 0; cc < 8; ++cc)
                    u.h[cc] = __float2bfloat16(interior ? fmaxf(acc[j][cc], 0.0f) : 0.0f);
                int pi = b * 900 + yy * 30 + xx;
                *(float4*)(hl + (size_t)pi * 128 + c0) = u.f4;
            }
        }
    }
}

// ---------------- Kernel 2: conv2 implicit GEMM — R4/R10 (verified best) ----
// frag-linear A (32KB linear staging, lane-linear conflict-free reads) + XOR-swizzled
// B (pre-swizzled gld_lds source); 8 waves x 128x64; one __syncthreads per K-tile;
// SGB program pinning {staging, ks0-frags, 1:1 MFMA:ds_read interleave}.
__global__ __launch_bounds__(512, 2) void k_conv2(const __hip_bfloat16* __restrict__ A,
                                                  const __hip_bfloat16* __restrict__ hl,
                                                  __hip_bfloat16* __restrict__ p) {
    __shared__ __align__(16) char smem[131072];   // 2 x (A 32KB | B 32KB)

    const int tid  = threadIdx.x;
    const int lane = tid & 63;
    const int w    = tid >> 6;          // 0..7
    const int hi   = lane >> 5;
    const int wqr  = w >> 2;            // 0..1  M-group (128 rows each)
    const int wqc  = w & 3;             // 0..3  N-group (64 cols each)

    const int bid = blockIdx.x;         // grid 1568 = 8 * 196
    const int nt  = (bid & 7) * 196 + (bid >> 3);   // bijective XCD swizzle
    const int n0  = nt << 8;            // 256 N per tile

    // ---- B staging addresses: wave w stages ch = 2w+q of each 16KB half ----
    uint32_t bSrc[2][2], ldsCh[2];
#pragma unroll
    for (int q = 0; q < 2; ++q) {
        int ch = 2 * w + q;
        int rl = ch * 8 + (lane >> 3);                 // row within 128-row half
        int ca = (lane & 7) ^ (rl & 7) ^ (ch & 3);     // pre-swizzled 16B column
        ldsCh[q] = (uint32_t)(ch * 1024);
#pragma unroll
        for (int hn = 0; hn < 2; ++hn) {
            int n = n0 + hn * 128 + rl;
            int b = n / 784; int rr = n - b * 784;
            int y = rr / 28; int xx = rr - y * 28;
            bSrc[q][hn] = (uint32_t)(((b * 30 + y) * 30 + xx) * 256 + ca * 16);
        }
    }

    // ---- B fragment read addresses (2 frags per wave), relative to B base ----
    uint32_t bRd[2]; int bSw[2];
#pragma unroll
    for (int j = 0; j < 2; ++j) {
        int r = wqc * 64 + j * 32 + (lane & 31);       // 0..255
        bRd[j] = (uint32_t)((r >> 7) * 16384 + (r & 127) * 128);
        bSw[j] = (r & 7) ^ ((r >> 3) & 3);
    }

    // ---- A read base: wave's m-half block, lane-linear ----
    const uint32_t aRd = (uint32_t)(wqr * 16384 + lane * 16);

    f32x16 acc[4][2];
#pragma unroll
    for (int i = 0; i < 4; ++i)
#pragma unroll
        for (int j = 0; j < 2; ++j) acc[i][j] = (f32x16)(0.0f);

    const char* Ab = (const char*)A;
    const char* Hb = (const char*)hl;

    auto stage = [&](int tt, char* dst) {
        // A: contiguous 32KB at tt*32768, fully linear
#pragma unroll
        for (int q = 0; q < 4; ++q)
            gld_lds16(Ab + (size_t)tt * 32768 + q * 8192 + tid * 16,
                      dst + q * 8192 + tid * 16);
        // B: pre-swizzled source, linear dest
        int kk = tt >> 1, half = tt & 1;
        int ky = kk / 3, kx = kk - ky * 3;
        uint32_t boff = (uint32_t)((ky * 30 + kx) * 256 + half * 128);
        gld_lds16(Hb + bSrc[0][0] + boff, dst + 32768 + ldsCh[0]);
        gld_lds16(Hb + bSrc[1][0] + boff, dst + 32768 + ldsCh[1]);
        gld_lds16(Hb + bSrc[0][1] + boff, dst + 49152 + ldsCh[0]);
        gld_lds16(Hb + bSrc[1][1] + boff, dst + 49152 + ldsCh[1]);
    };

    // ---- prologue: stage tile 0 into buf0 ----
    stage(0, smem);

#pragma unroll 1
    for (int t = 0; t < 17; ++t) {
        __syncthreads();             // drains staging of tile t (issued last iter)
        char* cur = smem + ((t & 1) << 16);
        const char* LA = cur + aRd;
        const char* LB = cur + 32768;
        stage(t + 1, smem + (((t + 1) & 1) << 16));   // unconditional: body branch-free

        bf16x8 aF[2][4], bF[2][2];
        // ks0 fragments
#pragma unroll
        for (int i = 0; i < 4; ++i)
            aF[0][i] = *(const bf16x8*)(LA + ((i * 4 + 0) << 10));
#pragma unroll
        for (int j = 0; j < 2; ++j)
            bF[0][j] = *(const bf16x8*)(LB + bRd[j] + ((uint32_t)((0 + hi) ^ bSw[j]) << 4));

#pragma unroll
        for (int ks = 0; ks < 4; ++ks) {
            const int c = ks & 1, nx = c ^ 1;
            if (ks < 3) {
#pragma unroll
                for (int i = 0; i < 4; ++i)
                    aF[nx][i] = *(const bf16x8*)(LA + ((i * 4 + ks + 1) << 10));
#pragma unroll
                for (int j = 0; j < 2; ++j)
                    bF[nx][j] = *(const bf16x8*)(LB + bRd[j] + ((uint32_t)(((ks + 1) * 2 + hi) ^ bSw[j]) << 4));
            }
#pragma unroll
            for (int i = 0; i < 4; ++i)
#pragma unroll
                for (int j = 0; j < 2; ++j)
                    acc[i][j] = __builtin_amdgcn_mfma_f32_32x32x16_bf16(aF[c][i], bF[c][j], acc[i][j], 0, 0, 0);
        }

        // ---- scheduling program for this region ----
        // masks: MFMA=0x8, VMEM|VMEM_READ=0x30, DS_READ=0x100
        __builtin_amdgcn_sched_group_barrier(0x030, 8, 0);   // staging first
        __builtin_amdgcn_sched_group_barrier(0x100, 6, 0);   // ks0 frags
#pragma unroll
        for (int ks = 0; ks < 3; ++ks) {
#pragma unroll
            for (int r = 0; r < 6; ++r) {
                __builtin_amdgcn_sched_group_barrier(0x008, 1, 0);
                __builtin_amdgcn_sched_group_barrier(0x100, 1, 0);
            }
            __builtin_amdgcn_sched_group_barrier(0x008, 2, 0);
        }
        __builtin_amdgcn_sched_group_barrier(0x008, 8, 0);   // ks3 MFMAs
    }

    // ---- drain: tile 17 from buf1, no staging ----
    {
        __syncthreads();
        char* cur = smem + 65536;
        const char* LA = cur + aRd;
        const char* LB = cur + 32768;

        bf16x8 aF[2][4], bF[2][2];
#pragma unroll
        for (int i = 0; i < 4; ++i)
            aF[0][i] = *(const bf16x8*)(LA + ((i * 4 + 0) << 10));
#pragma unroll
        for (int j = 0; j < 2; ++j)
            bF[0][j] = *(const bf16x8*)(LB + bRd[j] + ((uint32_t)((0 + hi) ^ bSw[j]) << 4));

#pragma unroll
        for (int ks = 0; ks < 4; ++ks) {
            const int c = ks & 1, nx = c ^ 1;
            if (ks < 3) {
#pragma unroll
                for (int i = 0; i < 4; ++i)
                    aF[nx][i] = *(const bf16x8*)(LA + ((i * 4 + ks + 1) << 10));
#pragma unroll
                for (int j = 0; j < 2; ++j)
                    bF[nx][j] = *(const bf16x8*)(LB + bRd[j] + ((uint32_t)(((ks + 1) * 2 + hi) ^ bSw[j]) << 4));
            }
#pragma unroll
            for (int i = 0; i < 4; ++i)
#pragma unroll
                for (int j = 0; j < 2; ++j)
                    acc[i][j] = __builtin_amdgcn_mfma_f32_32x32x16_bf16(aF[c][i], bF[c][j], acc[i][j], 0, 0, 0);
        }
    }

    // ---- epilogue: relu + mean over 8 consecutive M-rows; bf16 store ----
#pragma unroll
    for (int i = 0; i < 4; ++i) {
#pragma unroll
        for (int j = 0; j < 2; ++j) {
            f32x16 v = acc[i][j];
#pragma unroll
            for (int u = 0; u < 4; ++u) {
                float sv = fmaxf(v[4*u], 0.0f) + fmaxf(v[4*u+1], 0.0f)
                         + fmaxf(v[4*u+2], 0.0f) + fmaxf(v[4*u+3], 0.0f);
                sv += __shfl_xor(sv, 32, 64);
                if (hi == 0) {
                    int a = wqr * 16 + i * 4 + u;
                    int n = n0 + wqc * 64 + j * 32 + (lane & 31);
                    int b = n / 784; int rr = n - b * 784;
                    p[(b * 32 + a) * 784 + rr] = __float2bfloat16(sv * 0.125f);
                }
            }
        }
    }
}

// ---------------- Kernel 3: FC — 8 images/block to amortize fw reads ----------------
__global__ __launch_bounds__(256) void k_fc(const __hip_bfloat16* __restrict__ p,
                                            const float* __restrict__ fw,
                                            const float* __restrict__ fb,
                                            float* __restrict__ out) {
    int bg = blockIdx.x >> 2, ks = blockIdx.x & 3;   // bg: 0..63, 8 images each
    int tid = threadIdx.x;
    const float4* w4 = (const float4*)fw;
    float acc[8][10];
#pragma unroll
    for (int bb = 0; bb < 8; ++bb)
#pragma unroll
        for (int c = 0; c < 10; ++c) acc[bb][c] = 0.0f;

    for (int t = ks * 784 + tid; t < (ks + 1) * 784; t += 256) {
        float4 u0[10], u1[10];
#pragma unroll
        for (int c = 0; c < 10; ++c) {
            u0[c] = w4[c * 6272 + 2 * t];
            u1[c] = w4[c * 6272 + 2 * t + 1];
        }
#pragma unroll
        for (int bb = 0; bb < 8; ++bb) {
            union { bf16x8 v; __hip_bfloat16 h[8]; } u;
            u.v = *(const bf16x8*)(p + (size_t)(bg * 8 + bb) * 25088 + (size_t)t * 8);
            float vf[8];
#pragma unroll
            for (int e = 0; e < 8; ++e) vf[e] = __bfloat162float(u.h[e]);
#pragma unroll
            for (int c = 0; c < 10; ++c)
                acc[bb][c] += vf[0] * u0[c].x + vf[1] * u0[c].y + vf[2] * u0[c].z + vf[3] * u0[c].w
                            + vf[4] * u1[c].x + vf[5] * u1[c].y + vf[6] * u1[c].z + vf[7] * u1[c].w;
        }
    }

    __shared__ float red[8][10][4];
    int lane = tid & 63, wv = tid >> 6;
#pragma unroll
    for (int bb = 0; bb < 8; ++bb)
#pragma unroll
        for (int c = 0; c < 10; ++c) {
            float s = acc[bb][c];
#pragma unroll
            for (int o = 32; o > 0; o >>= 1) s += __shfl_down(s, o, 64);
            if (lane == 0) red[bb][c][wv] = s;
        }
    __syncthreads();
    if (tid < 80) {
        int bb = tid / 10, c = tid - bb * 10;
        float s = red[bb][c][0] + red[bb][c][1] + red[bb][c][2] + red[bb][c][3];
        if (ks == 0) s += fb[c];
        atomicAdd(&out[(bg * 8 + bb) * 10 + c], s);
    }
}

// ---------------- launch ----------------
extern "C" void kernel_launch(void* const* d_in, const int* in_sizes, int n_in,
                              void* d_out, int out_size, void* d_ws, size_t ws_size,
                              hipStream_t stream) {
    const float* x  = (const float*)d_in[0];
    const float* bw = (const float*)d_in[1];
    const float* w2 = (const float*)d_in[2];
    const float* fw = (const float*)d_in[3];
    const float* fb = (const float*)d_in[4];
    float* out = (float*)d_out;
    char* ws = (char*)d_ws;

    float*          w1   = (float*)(ws);
    __hip_bfloat16* Amat = (__hip_bfloat16*)(ws + 4608);
    __hip_bfloat16* hl   = (__hip_bfloat16*)(ws + 594432);
    __hip_bfloat16* p    = (__hip_bfloat16*)(ws + 118563328);

    hipMemsetAsync(d_out, 0, (size_t)out_size * sizeof(float), stream);
    k_rot  <<<1153, 256, 0, stream>>>(bw, w2, w1, Amat);
    k_conv1<<<512,  256, 0, stream>>>(x, w1, hl);
    k_conv2<<<1568, 512, 0, stream>>>(Amat, hl, p);
    k_fc   <<<256,  256, 0, stream>>>(p, fw, fb, out);
}